// Round 1
// baseline (5009.515 us; speedup 1.0000x reference)
//
#include <hip/hip_runtime.h>

// ---------------------------------------------------------------------------
// SlotMemoryRecurrentLM on MI355X (gfx950)
// Pipeline:
//  1. convert weights/emb to fp16, gather x = emb[ids]
//  2. GEMM1: gi = x @ w_ih^T + b_ih                      (fp16 MFMA, fp32 out)
//  3. GRU scan: persistent 256-WG dataflow kernel (4 chains x 64 WGs,
//     weights fp16 in VGPRs, h published via agent-scope stores, consumers
//     spin on 0xAA sentinel)
//  4. GEMM2 (fused): states @ [rq|wq|wv|wg|head_fc|rm]^T with per-column
//     epilogue (none/none/tanh/sigmoid/relu^2/sigmoid), also emits fp16 head
//  5. slot scan: 1 WG per batch, slots in LDS (pad 129), wave64 softmax
//  6. GEMM3: base = head @ head_proj^T ; GEMM4: retr = readvec @ s2f^T
//  7. mix = base + sig_rm * retr (fp16) ; GEMM5: logits = mix @ emb^T + bias
// All GEMMs are BT-form fp16 MFMA 16x16x32, 128x128 tile, BK=64,
// global_load_lds width-16 staging with XOR-8 swizzle (2-way LDS conflicts).
// ---------------------------------------------------------------------------

#define DI __device__ __forceinline__

typedef _Float16 f16x2 __attribute__((ext_vector_type(2)));
typedef _Float16 f16x8 __attribute__((ext_vector_type(8)));
typedef float    f32x4 __attribute__((ext_vector_type(4)));

#define GLD16(gp, lp) __builtin_amdgcn_global_load_lds(                      \
    (const __attribute__((address_space(1))) void*)(gp),                     \
    (__attribute__((address_space(3))) void*)(lp), 16, 0, 0)

DI unsigned pack_h2(float a, float b) {
  f16x2 p; p[0] = (_Float16)a; p[1] = (_Float16)b;
  return __builtin_bit_cast(unsigned, p);
}
DI float sigmoid_acc(float x) { return 1.f / (1.f + expf(-x)); }

// ------------------------- generic fp16 BT GEMM ----------------------------
// C[M,N](f32) = A[M,K](f16,row) @ B[N,K](f16,row)^T + bias[N], epilogue EPI.
// grid = (N/128, M/128), block = 256 (4 waves, 2x2 of 64x64).
template <int EPI>
__global__ __launch_bounds__(256) void k_gemm_bt(
    const _Float16* __restrict__ A, const _Float16* __restrict__ B,
    const float* __restrict__ bias, float* __restrict__ C,
    _Float16* __restrict__ aux, int N, int K)
{
  __shared__ __attribute__((aligned(16))) _Float16 Ah[128 * 64];
  __shared__ __attribute__((aligned(16))) _Float16 Bh[128 * 64];
  const int tid = threadIdx.x;
  const int wv = tid >> 6, ln = tid & 63;
  const int bm = blockIdx.y << 7, bn = blockIdx.x << 7;
  const int wm = (wv >> 1) << 6, wn = (wv & 1) << 6;
  const int lrow = ln & 15, lk = ln >> 4;
  const int srow = ln >> 3, sseg = ln & 7;

  f32x4 acc[4][4];
#pragma unroll
  for (int i = 0; i < 4; ++i)
#pragma unroll
    for (int j = 0; j < 4; ++j) acc[i][j] = (f32x4){0.f, 0.f, 0.f, 0.f};

  for (int kt = 0; kt < K; kt += 64) {
#pragma unroll
    for (int c = 0; c < 4; ++c) {
      int ch = (wv << 2) + c;
      int row = (ch << 3) + srow;            // 0..127
      int seg = sseg ^ (row & 7);            // XOR-8 swizzle
      GLD16(A + (size_t)(bm + row) * K + kt + (seg << 3), &Ah[ch << 9]);
      GLD16(B + (size_t)(bn + row) * K + kt + (seg << 3), &Bh[ch << 9]);
    }
    __syncthreads();                         // waits vmcnt(0) before barrier
#pragma unroll
    for (int ks = 0; ks < 2; ++ks) {
      f16x8 af[4], bf[4];
#pragma unroll
      for (int i = 0; i < 4; ++i) {
        int row = wm + (i << 4) + lrow;
        int phys = ((ks << 2) + lk) ^ (row & 7);
        af[i] = *(const f16x8*)&Ah[(row << 6) + (phys << 3)];
      }
#pragma unroll
      for (int j = 0; j < 4; ++j) {
        int row = wn + (j << 4) + lrow;
        int phys = ((ks << 2) + lk) ^ (row & 7);
        bf[j] = *(const f16x8*)&Bh[(row << 6) + (phys << 3)];
      }
#pragma unroll
      for (int i = 0; i < 4; ++i)
#pragma unroll
        for (int j = 0; j < 4; ++j)
          acc[i][j] = __builtin_amdgcn_mfma_f32_16x16x32_f16(af[i], bf[j], acc[i][j], 0, 0, 0);
    }
    __syncthreads();
  }
  // epilogue: C/D layout col = lane&15, row = (lane>>4)*4 + reg  [m89/m91]
#pragma unroll
  for (int i = 0; i < 4; ++i) {
    int row0 = bm + wm + (i << 4) + (lk << 2);
#pragma unroll
    for (int j = 0; j < 4; ++j) {
      int col = bn + wn + (j << 4) + lrow;
      float bv = bias[col];
#pragma unroll
      for (int r = 0; r < 4; ++r) {
        float v = acc[i][j][r] + bv;
        if (EPI == 1) {
          if (col < 256) { /* rq,wq: none */ }
          else if (col < 384) v = tanhf(v);                    // wv
          else if (col < 448) v = sigmoid_acc(v);              // wg
          else if (col < 2496) { v = fmaxf(v, 0.f); v = v * v; } // head relu^2
          else v = sigmoid_acc(v);                             // rm (pad cols harmless)
        }
        C[(size_t)(row0 + r) * N + col] = v;
        if (EPI == 1 && col >= 448 && col < 2496)
          aux[(size_t)(row0 + r) * 2048 + (col - 448)] = (_Float16)v;
      }
    }
  }
}

// ------------------------------ GRU scan -----------------------------------
// 256 WGs = 4 chains x 64 slices of 16 hidden units. Weights (48 rows x 1024,
// fp16) live in VGPRs. h published to h_steps (agent sc1 atomic stores);
// consumers spin until value != 0xAAAAAAAA sentinel.
__global__ __launch_bounds__(256) void k_gru(
    const float* __restrict__ gi,     // [4096][3072]
    const float* __restrict__ w_hh,   // [3072][1024]
    const float* __restrict__ b_hh,   // [3072]
    float* __restrict__ h_steps,      // [4][1024][1024], pre-filled 0xAA
    _Float16* __restrict__ states_h)  // [4096][1024]
{
  const int tid = threadIdx.x;
  const int w = tid >> 6, l = tid & 63;
  const int xid = blockIdx.x & 7, sid = blockIdx.x >> 3;   // XCD-friendly split
  const int chain = xid >> 1;
  const int slice = ((xid & 1) << 5) + sid;                // 0..63
  const int u0 = slice << 4;
  const int G = (w << 2) + (l >> 4);                       // 0..15: row group
  const int j = l & 15;                                    // k-slice id

  __shared__ __attribute__((aligned(16))) unsigned hh2[512]; // h as half2
  __shared__ float rsum[48];
  __shared__ float bhhs[48];

  // preload weights: rows i = G*3+c ; i<16 -> r(u0+i), <32 -> z, <48 -> n.
  // lane j holds k in {q*64 + j*4 + 0..3}, coalesced float4 reads.
  unsigned wreg[3][32];
#pragma unroll
  for (int c = 0; c < 3; ++c) {
    int i = G * 3 + c;
    int R = ((i >> 4) << 10) + u0 + (i & 15);
    const float* wrow = w_hh + ((size_t)R << 10);
#pragma unroll
    for (int q = 0; q < 16; ++q) {
      float4 v = *(const float4*)(wrow + (q << 6) + (j << 2));
      wreg[c][2 * q]     = pack_h2(v.x, v.y);
      wreg[c][2 * q + 1] = pack_h2(v.z, v.w);
    }
  }
  if (tid < 48)
    bhhs[tid] = b_hh[((tid >> 4) << 10) + u0 + (tid & 15)];

  float h_old = 0.f;                    // wave0 lanes 0..15: unit u0+l
  float g_r = 0.f, g_z = 0.f, g_n = 0.f;
  if (w == 0 && l < 16) {
    size_t gb = ((size_t)chain << 10) * 3072;
    g_r = gi[gb + u0 + l];
    g_z = gi[gb + 1024 + u0 + l];
    g_n = gi[gb + 2048 + u0 + l];
  }
  __syncthreads();

  for (int t = 0; t < 1024; ++t) {
    size_t bt = ((size_t)chain << 10) + t;
    if (t == 0) {
      hh2[2 * tid] = 0u; hh2[2 * tid + 1] = 0u;      // h_{-1} = 0
    } else {
      const unsigned long long* hp =
          (const unsigned long long*)(h_steps + ((bt - 1) << 10));
      unsigned long long d0, d1;
      for (;;) {
        d0 = __hip_atomic_load(hp + 2 * tid, __ATOMIC_RELAXED, __HIP_MEMORY_SCOPE_AGENT);
        if ((unsigned)d0 != 0xAAAAAAAAu && (unsigned)(d0 >> 32) != 0xAAAAAAAAu) break;
        __builtin_amdgcn_s_sleep(1);
      }
      for (;;) {
        d1 = __hip_atomic_load(hp + 2 * tid + 1, __ATOMIC_RELAXED, __HIP_MEMORY_SCOPE_AGENT);
        if ((unsigned)d1 != 0xAAAAAAAAu && (unsigned)(d1 >> 32) != 0xAAAAAAAAu) break;
        __builtin_amdgcn_s_sleep(1);
      }
      float f0 = __uint_as_float((unsigned)d0);
      float f1 = __uint_as_float((unsigned)(d0 >> 32));
      float f2 = __uint_as_float((unsigned)d1);
      float f3 = __uint_as_float((unsigned)(d1 >> 32));
      hh2[2 * tid]     = pack_h2(f0, f1);
      hh2[2 * tid + 1] = pack_h2(f2, f3);
    }
    __syncthreads();

    float a0 = 0.f, a1 = 0.f, a2 = 0.f;
#pragma unroll
    for (int q = 0; q < 16; ++q) {
      uint2 hu = *(const uint2*)&hh2[(q << 5) + (j << 1)];
      f16x2 h0 = __builtin_bit_cast(f16x2, hu.x);
      f16x2 h1 = __builtin_bit_cast(f16x2, hu.y);
      a0 = __builtin_amdgcn_fdot2(__builtin_bit_cast(f16x2, wreg[0][2 * q]),     h0, a0, false);
      a0 = __builtin_amdgcn_fdot2(__builtin_bit_cast(f16x2, wreg[0][2 * q + 1]), h1, a0, false);
      a1 = __builtin_amdgcn_fdot2(__builtin_bit_cast(f16x2, wreg[1][2 * q]),     h0, a1, false);
      a1 = __builtin_amdgcn_fdot2(__builtin_bit_cast(f16x2, wreg[1][2 * q + 1]), h1, a1, false);
      a2 = __builtin_amdgcn_fdot2(__builtin_bit_cast(f16x2, wreg[2][2 * q]),     h0, a2, false);
      a2 = __builtin_amdgcn_fdot2(__builtin_bit_cast(f16x2, wreg[2][2 * q + 1]), h1, a2, false);
    }
#pragma unroll
    for (int m = 1; m <= 8; m <<= 1) {
      a0 += __shfl_xor(a0, m, 64);
      a1 += __shfl_xor(a1, m, 64);
      a2 += __shfl_xor(a2, m, 64);
    }
    if (j == 0) { rsum[G * 3] = a0; rsum[G * 3 + 1] = a1; rsum[G * 3 + 2] = a2; }
    __syncthreads();

    if (w == 0 && l < 16) {
      float sr = rsum[l] + bhhs[l];
      float sz = rsum[16 + l] + bhhs[16 + l];
      float sn = rsum[32 + l] + bhhs[32 + l];
      float r = 1.f / (1.f + __expf(-(g_r + sr)));
      float z = 1.f / (1.f + __expf(-(g_z + sz)));
      float arg = g_n + r * sn;
      float n = 1.f - 2.f / (__expf(2.f * arg) + 1.f);   // tanh
      h_old = (1.f - z) * n + z * h_old;
      __hip_atomic_store(h_steps + (bt << 10) + u0 + l, h_old,
                         __ATOMIC_RELAXED, __HIP_MEMORY_SCOPE_AGENT);
      states_h[(bt << 10) + u0 + l] = (_Float16)h_old;
      if (t + 1 < 1024) {
        size_t gb = (bt + 1) * 3072;
        g_r = gi[gb + u0 + l];
        g_z = gi[gb + 1024 + u0 + l];
        g_n = gi[gb + 2048 + u0 + l];
      }
    }
    __syncthreads();
  }
}

// ------------------------------ slot scan ----------------------------------
// 1 WG per batch. slots[64][128] in LDS (stride 129: 2-way banks only).
__global__ __launch_bounds__(256) void k_slot(
    const float* __restrict__ act2,       // [4096][3072]: rq|wq|wv|wg|...
    const float* __restrict__ slot_init,  // [64][128]
    _Float16* __restrict__ rv_h)          // [4096][128]
{
  const int b = blockIdx.x;
  const int tid = threadIdx.x;
  __shared__ float slots[64 * 129];
  __shared__ __attribute__((aligned(16))) float lin[448];
  __shared__ float pr[256], pw[256];
  __shared__ float ar[64], aws[64];
  __shared__ float rvp[256];

  for (int k = tid; k < 8192; k += 256)
    slots[(k >> 7) * 129 + (k & 127)] = slot_init[k];

  float2 pf = {0.f, 0.f};
  if (tid < 224)
    pf = *(const float2*)(act2 + ((size_t)b << 10) * 3072 + (tid << 1));

  const int s_ = tid & 63, q_ = tid >> 6;

  for (int t = 0; t < 1024; ++t) {
    size_t bt = ((size_t)b << 10) + t;
    if (tid < 224) *(float2*)&lin[tid << 1] = pf;
    __syncthreads();
    if (tid < 224 && t + 1 < 1024)
      pf = *(const float2*)(act2 + (bt + 1) * 3072 + (tid << 1));

    {   // partial dots: thread (s, quarter q)
      const float* srow = &slots[s_ * 129 + (q_ << 5)];
      const float* qv  = &lin[q_ << 5];
      const float* wqv = &lin[128 + (q_ << 5)];
      float p0 = 0.f, p1 = 0.f;
#pragma unroll
      for (int i = 0; i < 32; ++i) {
        float sv = srow[i];
        p0 += sv * qv[i];
        p1 += sv * wqv[i];
      }
      pr[(q_ << 6) + s_] = p0;
      pw[(q_ << 6) + s_] = p1;
    }
    __syncthreads();
    if (tid < 64) {           // wave0: read softmax
      float lg = pr[tid] + pr[64 + tid] + pr[128 + tid] + pr[192 + tid];
      float mx = lg;
#pragma unroll
      for (int m = 1; m <= 32; m <<= 1) mx = fmaxf(mx, __shfl_xor(mx, m, 64));
      float e = __expf(lg - mx);
      float sm = e;
#pragma unroll
      for (int m = 1; m <= 32; m <<= 1) sm += __shfl_xor(sm, m, 64);
      ar[tid] = e / sm;
    } else if (tid < 128) {   // wave1: write softmax * gate
      int s = tid - 64;
      float lg = pw[s] + pw[64 + s] + pw[128 + s] + pw[192 + s];
      float mx = lg;
#pragma unroll
      for (int m = 1; m <= 32; m <<= 1) mx = fmaxf(mx, __shfl_xor(mx, m, 64));
      float e = __expf(lg - mx);
      float sm = e;
#pragma unroll
      for (int m = 1; m <= 32; m <<= 1) sm += __shfl_xor(sm, m, 64);
      aws[s] = (e / sm) * lin[384 + s];
    }
    __syncthreads();
    {   // read_vec partials: thread (d, slot-half)
      int d = tid & 127, sh = tid >> 7;
      float rv = 0.f;
#pragma unroll
      for (int i = 0; i < 32; ++i) {
        int s = (sh << 5) + i;
        rv += ar[s] * slots[s * 129 + d];
      }
      rvp[(sh << 7) + d] = rv;
    }
    __syncthreads();
    if (tid < 128)
      rv_h[(bt << 7) + tid] = (_Float16)(rvp[tid] + rvp[128 + tid]);
    {   // slot update: slots = slots*(1-ws) + wv*ws
      int s = tid >> 2, c = tid & 3;
      float wsv = aws[s];
      float fr = 1.f - wsv;
      const float* wvq = &lin[256 + (c << 5)];
      float* srw = &slots[s * 129 + (c << 5)];
#pragma unroll
      for (int i = 0; i < 32; ++i)
        srw[i] = srw[i] * fr + wvq[i] * wsv;
    }
    __syncthreads();
  }
}

// ---------------------------- small utilities ------------------------------
__global__ void k_f32_to_f16_v8(const float* __restrict__ src,
                                _Float16* __restrict__ dst, int n8) {
  int i = blockIdx.x * 256 + threadIdx.x;
  if (i >= n8) return;
  float4 a = *(const float4*)(src + ((size_t)i << 3));
  float4 b = *(const float4*)(src + ((size_t)i << 3) + 4);
  f16x8 o;
  o[0] = (_Float16)a.x; o[1] = (_Float16)a.y; o[2] = (_Float16)a.z; o[3] = (_Float16)a.w;
  o[4] = (_Float16)b.x; o[5] = (_Float16)b.y; o[6] = (_Float16)b.z; o[7] = (_Float16)b.w;
  *(f16x8*)(dst + ((size_t)i << 3)) = o;
}

__global__ void k_build_wcat(const float* __restrict__ rq, const float* __restrict__ wq,
                             const float* __restrict__ wvw, const float* __restrict__ wg,
                             const float* __restrict__ hf, const float* __restrict__ rm,
                             _Float16* __restrict__ out) {
  int idx = blockIdx.x * 256 + threadIdx.x;
  if (idx >= 3072 * 1024) return;
  int row = idx >> 10, col = idx & 1023;
  float v;
  if      (row < 128)  v = rq[row * 1024 + col];
  else if (row < 256)  v = wq[(row - 128) * 1024 + col];
  else if (row < 384)  v = wvw[(row - 256) * 1024 + col];
  else if (row < 448)  v = wg[(row - 384) * 1024 + col];
  else if (row < 2496) v = hf[(row - 448) * 1024 + col];
  else if (row < 3008) v = rm[(row - 2496) * 1024 + col];
  else v = 0.f;
  out[idx] = (_Float16)v;
}

__global__ void k_build_biascat(const float* __restrict__ rq, const float* __restrict__ wq,
                                const float* __restrict__ wvb, const float* __restrict__ wg,
                                const float* __restrict__ hf, const float* __restrict__ rm,
                                float* __restrict__ out) {
  int r = blockIdx.x * 256 + threadIdx.x;
  if (r >= 3072) return;
  float v;
  if      (r < 128)  v = rq[r];
  else if (r < 256)  v = wq[r - 128];
  else if (r < 384)  v = wvb[r - 256];
  else if (r < 448)  v = wg[r - 384];
  else if (r < 2496) v = hf[r - 448];
  else if (r < 3008) v = rm[r - 2496];
  else v = 0.f;
  out[r] = v;
}

__global__ void k_gather_x(const int* __restrict__ ids,
                           const _Float16* __restrict__ emb_h,
                           _Float16* __restrict__ x_h) {
  int row = blockIdx.x;                       // 4096
  int id = ids[row];
  const unsigned* s = (const unsigned*)(emb_h + ((size_t)id << 9));
  unsigned* d = (unsigned*)(x_h + ((size_t)row << 9));
  d[threadIdx.x] = s[threadIdx.x];            // 256 x 4B = 512 halves
}

__global__ void k_fill_u32(unsigned* __restrict__ p, unsigned v, int n) {
  int i = blockIdx.x * 256 + threadIdx.x;
  if (i < n) p[i] = v;
}

__global__ void k_mix(const float* __restrict__ base, const float* __restrict__ act2,
                      const float* __restrict__ retr, _Float16* __restrict__ out) {
  int idx = blockIdx.x * 256 + threadIdx.x;
  if (idx >= 4096 * 512) return;
  int r = idx >> 9, e = idx & 511;
  float v = base[idx] + act2[(size_t)r * 3072 + 2496 + e] * retr[idx];
  out[idx] = (_Float16)v;
}

// ------------------------------- launcher ----------------------------------
extern "C" void kernel_launch(void* const* d_in, const int* in_sizes, int n_in,
                              void* d_out, int out_size, void* d_ws, size_t ws_size,
                              hipStream_t stream)
{
  const int*   ids   = (const int*)d_in[0];
  const float* emb   = (const float*)d_in[1];
  const float* w_ih  = (const float*)d_in[2];
  const float* w_hh  = (const float*)d_in[3];
  const float* b_ih  = (const float*)d_in[4];
  const float* b_hh  = (const float*)d_in[5];
  const float* hf_w  = (const float*)d_in[6];
  const float* hf_b  = (const float*)d_in[7];
  const float* hp_w  = (const float*)d_in[8];
  const float* hp_b  = (const float*)d_in[9];
  const float* o_b   = (const float*)d_in[10];
  const float* sinit = (const float*)d_in[11];
  const float* rq_w  = (const float*)d_in[12];
  const float* rq_b  = (const float*)d_in[13];
  const float* wq_w  = (const float*)d_in[14];
  const float* wq_b  = (const float*)d_in[15];
  const float* wv_w  = (const float*)d_in[16];
  const float* wv_b  = (const float*)d_in[17];
  const float* wg_w  = (const float*)d_in[18];
  const float* wg_b  = (const float*)d_in[19];
  const float* rm_w  = (const float*)d_in[20];
  const float* rm_b  = (const float*)d_in[21];
  const float* s2f_w = (const float*)d_in[22];
  const float* s2f_b = (const float*)d_in[23];

  char* ws = (char*)d_ws;
  _Float16* emb_h   = (_Float16*)(ws + 0);          // 32,768,000
  _Float16* x_h     = (_Float16*)(ws + 32768000);   //  4,194,304
  _Float16* wih_h   = (_Float16*)(ws + 36962304);   //  3,145,728
  _Float16* wcat_h  = (_Float16*)(ws + 40108032);   //  6,291,456
  float*    biascat = (float*)   (ws + 46399488);   //     12,288
  _Float16* hpw_h   = (_Float16*)(ws + 46411776);   //  2,097,152
  _Float16* s2f_h   = (_Float16*)(ws + 48508928);   //    131,072
  float*    gi      = (float*)   (ws + 48640000);   // 50,331,648
  float*    act2    = (float*)   (ws + 98971648);   // 50,331,648
  float*    h_steps = (float*)   (ws + 149303296);  // 16,777,216
  _Float16* states_h= (_Float16*)(ws + 166080512);  //  8,388,608
  _Float16* headh   = (_Float16*)(ws + 174469120);  // 16,777,216
  _Float16* rv_h    = (_Float16*)(ws + 191246336);  //  1,048,576
  float*    base    = (float*)   (ws + 192294912);  //  8,388,608
  float*    retr    = (float*)   (ws + 200683520);  //  8,388,608
  _Float16* mixed_h = (_Float16*)(ws + 209072128);  //  4,194,304  -> ~213 MB
  float* out = (float*)d_out;

  // --- prep (fp16 conversions / packing) ---
  k_f32_to_f16_v8<<<8000, 256, 0, stream>>>(emb, emb_h, 2048000);
  k_f32_to_f16_v8<<<768, 256, 0, stream>>>(w_ih, wih_h, 196608);
  k_f32_to_f16_v8<<<512, 256, 0, stream>>>(hp_w, hpw_h, 131072);
  k_f32_to_f16_v8<<<32, 256, 0, stream>>>(s2f_w, s2f_h, 8192);
  k_build_wcat<<<12288, 256, 0, stream>>>(rq_w, wq_w, wv_w, wg_w, hf_w, rm_w, wcat_h);
  k_build_biascat<<<12, 256, 0, stream>>>(rq_b, wq_b, wv_b, wg_b, hf_b, rm_b, biascat);
  k_gather_x<<<4096, 256, 0, stream>>>(ids, emb_h, x_h);
  k_fill_u32<<<16384, 256, 0, stream>>>((unsigned*)h_steps, 0xAAAAAAAAu, 4194304);

  // --- gi = x @ w_ih^T + b_ih ---
  k_gemm_bt<0><<<dim3(24, 32), 256, 0, stream>>>(x_h, wih_h, b_ih, gi, nullptr, 3072, 512);

  // --- GRU scan (persistent dataflow) ---
  k_gru<<<256, 256, 0, stream>>>(gi, w_hh, b_hh, h_steps, states_h);

  // --- fused states projections (rq|wq|wv|wg|head|rm) ---
  k_gemm_bt<1><<<dim3(24, 32), 256, 0, stream>>>(states_h, wcat_h, biascat, act2, headh, 3072, 1024);

  // --- slot memory scan ---
  k_slot<<<4, 256, 0, stream>>>(act2, sinit, rv_h);

  // --- head_proj, s2f, mix, logits ---
  k_gemm_bt<0><<<dim3(4, 32), 256, 0, stream>>>(headh, hpw_h, hp_b, base, nullptr, 512, 2048);
  k_gemm_bt<0><<<dim3(4, 32), 256, 0, stream>>>(rv_h, s2f_h, s2f_b, retr, nullptr, 512, 128);
  k_mix<<<8192, 256, 0, stream>>>(base, act2, retr, mixed_h);
  k_gemm_bt<0><<<dim3(250, 32), 256, 0, stream>>>(mixed_h, emb_h, o_b, out, nullptr, 32000, 512);
}

// Round 2
// 4110.563 us; speedup vs baseline: 1.2187x; 1.2187x over previous
//
#include <hip/hip_runtime.h>

// ---------------------------------------------------------------------------
// SlotMemoryRecurrentLM on MI355X (gfx950)  — round 2
//  * k_slot rewritten: XOR-swizzled float4 slots in LDS (conflict-free b128),
//    fused read_vec+update pass, 3 barriers/step, rv-fold hidden in softmax
//    phase, lin double-buffered one step ahead.
//  * k_gru: h published as packed fp16 pairs; ONE 8-byte poll per thread
//    (was two serial), 2 barriers/step, split dot accumulators.
// ---------------------------------------------------------------------------

#define DI __device__ __forceinline__

typedef _Float16 f16x2 __attribute__((ext_vector_type(2)));
typedef _Float16 f16x8 __attribute__((ext_vector_type(8)));
typedef float    f32x4 __attribute__((ext_vector_type(4)));

#define GLD16(gp, lp) __builtin_amdgcn_global_load_lds(                      \
    (const __attribute__((address_space(1))) void*)(gp),                     \
    (__attribute__((address_space(3))) void*)(lp), 16, 0, 0)

DI unsigned pack_h2(float a, float b) {
  f16x2 p; p[0] = (_Float16)a; p[1] = (_Float16)b;
  return __builtin_bit_cast(unsigned, p);
}
DI float sigmoid_acc(float x) { return 1.f / (1.f + expf(-x)); }

// ------------------------- generic fp16 BT GEMM ----------------------------
template <int EPI>
__global__ __launch_bounds__(256) void k_gemm_bt(
    const _Float16* __restrict__ A, const _Float16* __restrict__ B,
    const float* __restrict__ bias, float* __restrict__ C,
    _Float16* __restrict__ aux, int N, int K)
{
  __shared__ __attribute__((aligned(16))) _Float16 Ah[128 * 64];
  __shared__ __attribute__((aligned(16))) _Float16 Bh[128 * 64];
  const int tid = threadIdx.x;
  const int wv = tid >> 6, ln = tid & 63;
  const int bm = blockIdx.y << 7, bn = blockIdx.x << 7;
  const int wm = (wv >> 1) << 6, wn = (wv & 1) << 6;
  const int lrow = ln & 15, lk = ln >> 4;
  const int srow = ln >> 3, sseg = ln & 7;

  f32x4 acc[4][4];
#pragma unroll
  for (int i = 0; i < 4; ++i)
#pragma unroll
    for (int j = 0; j < 4; ++j) acc[i][j] = (f32x4){0.f, 0.f, 0.f, 0.f};

  for (int kt = 0; kt < K; kt += 64) {
#pragma unroll
    for (int c = 0; c < 4; ++c) {
      int ch = (wv << 2) + c;
      int row = (ch << 3) + srow;
      int seg = sseg ^ (row & 7);
      GLD16(A + (size_t)(bm + row) * K + kt + (seg << 3), &Ah[ch << 9]);
      GLD16(B + (size_t)(bn + row) * K + kt + (seg << 3), &Bh[ch << 9]);
    }
    __syncthreads();
#pragma unroll
    for (int ks = 0; ks < 2; ++ks) {
      f16x8 af[4], bf[4];
#pragma unroll
      for (int i = 0; i < 4; ++i) {
        int row = wm + (i << 4) + lrow;
        int phys = ((ks << 2) + lk) ^ (row & 7);
        af[i] = *(const f16x8*)&Ah[(row << 6) + (phys << 3)];
      }
#pragma unroll
      for (int j = 0; j < 4; ++j) {
        int row = wn + (j << 4) + lrow;
        int phys = ((ks << 2) + lk) ^ (row & 7);
        bf[j] = *(const f16x8*)&Bh[(row << 6) + (phys << 3)];
      }
#pragma unroll
      for (int i = 0; i < 4; ++i)
#pragma unroll
        for (int j = 0; j < 4; ++j)
          acc[i][j] = __builtin_amdgcn_mfma_f32_16x16x32_f16(af[i], bf[j], acc[i][j], 0, 0, 0);
    }
    __syncthreads();
  }
#pragma unroll
  for (int i = 0; i < 4; ++i) {
    int row0 = bm + wm + (i << 4) + (lk << 2);
#pragma unroll
    for (int j = 0; j < 4; ++j) {
      int col = bn + wn + (j << 4) + lrow;
      float bv = bias[col];
#pragma unroll
      for (int r = 0; r < 4; ++r) {
        float v = acc[i][j][r] + bv;
        if (EPI == 1) {
          if (col < 256) { }
          else if (col < 384) v = tanhf(v);
          else if (col < 448) v = sigmoid_acc(v);
          else if (col < 2496) { v = fmaxf(v, 0.f); v = v * v; }
          else v = sigmoid_acc(v);
        }
        C[(size_t)(row0 + r) * N + col] = v;
        if (EPI == 1 && col >= 448 && col < 2496)
          aux[(size_t)(row0 + r) * 2048 + (col - 448)] = (_Float16)v;
      }
    }
  }
}

// ------------------------------ GRU scan -----------------------------------
// 256 WGs = 4 chains x 64 slices of 16 hidden units. h published as packed
// fp16 pairs (512 dwords/step); each consumer thread does ONE 8B poll.
__global__ __launch_bounds__(256) void k_gru(
    const float* __restrict__ gi,     // [4096][3072]
    const float* __restrict__ w_hh,   // [3072][1024]
    const float* __restrict__ b_hh,   // [3072]
    unsigned* __restrict__ h16,       // [4][1024][512] packed half2, 0xAA-filled
    _Float16* __restrict__ states_h)  // [4096][1024]
{
  const int tid = threadIdx.x;
  const int w = tid >> 6, l = tid & 63;
  const int xid = blockIdx.x & 7, sid = blockIdx.x >> 3;
  const int chain = xid >> 1;
  const int slice = ((xid & 1) << 5) + sid;                // 0..63
  const int u0 = slice << 4;
  const int G = (w << 2) + (l >> 4);                       // 0..15
  const int j = l & 15;

  __shared__ __attribute__((aligned(16))) unsigned hh2[512];
  __shared__ float rsum[48];
  __shared__ float bhhs[48];

  unsigned wreg[3][32];
#pragma unroll
  for (int c = 0; c < 3; ++c) {
    int i = G * 3 + c;
    int R = ((i >> 4) << 10) + u0 + (i & 15);
    const float* wrow = w_hh + ((size_t)R << 10);
#pragma unroll
    for (int q = 0; q < 16; ++q) {
      float4 v = *(const float4*)(wrow + (q << 6) + (j << 2));
      wreg[c][2 * q]     = pack_h2(v.x, v.y);
      wreg[c][2 * q + 1] = pack_h2(v.z, v.w);
    }
  }
  if (tid < 48)
    bhhs[tid] = b_hh[((tid >> 4) << 10) + u0 + (tid & 15)];

  float h_old = 0.f;
  float g_r = 0.f, g_z = 0.f, g_n = 0.f;
  if (w == 0 && l < 16) {
    size_t gb = ((size_t)chain << 10) * 3072;
    g_r = gi[gb + u0 + l];
    g_z = gi[gb + 1024 + u0 + l];
    g_n = gi[gb + 2048 + u0 + l];
  }
  __syncthreads();

  for (int t = 0; t < 1024; ++t) {
    size_t bt = ((size_t)chain << 10) + t;
    if (t == 0) {
      hh2[2 * tid] = 0u; hh2[2 * tid + 1] = 0u;
    } else {
      const unsigned long long* hp =
          (const unsigned long long*)(h16 + ((bt - 1) << 9));
      unsigned long long d;
      for (;;) {
        d = __hip_atomic_load(hp + tid, __ATOMIC_RELAXED, __HIP_MEMORY_SCOPE_AGENT);
        if ((unsigned)d != 0xAAAAAAAAu && (unsigned)(d >> 32) != 0xAAAAAAAAu) break;
        __builtin_amdgcn_s_sleep(1);
      }
      hh2[2 * tid]     = (unsigned)d;
      hh2[2 * tid + 1] = (unsigned)(d >> 32);
    }
    __syncthreads();

    // dots: 6 chains of 16 fdot2 each
    float a0 = 0.f, a1 = 0.f, a2 = 0.f, a3 = 0.f, a4 = 0.f, a5 = 0.f;
#pragma unroll
    for (int q = 0; q < 16; q += 2) {
      uint2 hA = *(const uint2*)&hh2[(q << 5) + (j << 1)];
      uint2 hB = *(const uint2*)&hh2[((q + 1) << 5) + (j << 1)];
      f16x2 hA0 = __builtin_bit_cast(f16x2, hA.x), hA1 = __builtin_bit_cast(f16x2, hA.y);
      f16x2 hB0 = __builtin_bit_cast(f16x2, hB.x), hB1 = __builtin_bit_cast(f16x2, hB.y);
      a0 = __builtin_amdgcn_fdot2(__builtin_bit_cast(f16x2, wreg[0][2 * q]),     hA0, a0, false);
      a0 = __builtin_amdgcn_fdot2(__builtin_bit_cast(f16x2, wreg[0][2 * q + 1]), hA1, a0, false);
      a3 = __builtin_amdgcn_fdot2(__builtin_bit_cast(f16x2, wreg[0][2 * q + 2]), hB0, a3, false);
      a3 = __builtin_amdgcn_fdot2(__builtin_bit_cast(f16x2, wreg[0][2 * q + 3]), hB1, a3, false);
      a1 = __builtin_amdgcn_fdot2(__builtin_bit_cast(f16x2, wreg[1][2 * q]),     hA0, a1, false);
      a1 = __builtin_amdgcn_fdot2(__builtin_bit_cast(f16x2, wreg[1][2 * q + 1]), hA1, a1, false);
      a4 = __builtin_amdgcn_fdot2(__builtin_bit_cast(f16x2, wreg[1][2 * q + 2]), hB0, a4, false);
      a4 = __builtin_amdgcn_fdot2(__builtin_bit_cast(f16x2, wreg[1][2 * q + 3]), hB1, a4, false);
      a2 = __builtin_amdgcn_fdot2(__builtin_bit_cast(f16x2, wreg[2][2 * q]),     hA0, a2, false);
      a2 = __builtin_amdgcn_fdot2(__builtin_bit_cast(f16x2, wreg[2][2 * q + 1]), hA1, a2, false);
      a5 = __builtin_amdgcn_fdot2(__builtin_bit_cast(f16x2, wreg[2][2 * q + 2]), hB0, a5, false);
      a5 = __builtin_amdgcn_fdot2(__builtin_bit_cast(f16x2, wreg[2][2 * q + 3]), hB1, a5, false);
    }
    a0 += a3; a1 += a4; a2 += a5;
#pragma unroll
    for (int m = 1; m <= 8; m <<= 1) {
      a0 += __shfl_xor(a0, m, 64);
      a1 += __shfl_xor(a1, m, 64);
      a2 += __shfl_xor(a2, m, 64);
    }
    if (j == 0) { rsum[G * 3] = a0; rsum[G * 3 + 1] = a1; rsum[G * 3 + 2] = a2; }
    __syncthreads();

    if (w == 0 && l < 16) {
      float sr = rsum[l] + bhhs[l];
      float sz = rsum[16 + l] + bhhs[16 + l];
      float sn = rsum[32 + l] + bhhs[32 + l];
      float r = 1.f / (1.f + __expf(-(g_r + sr)));
      float z = 1.f / (1.f + __expf(-(g_z + sz)));
      float arg = g_n + r * sn;
      float n = 1.f - 2.f / (__expf(2.f * arg) + 1.f);
      h_old = (1.f - z) * n + z * h_old;
      float hpart = __shfl_xor(h_old, 1, 64);
      if ((l & 1) == 0) {
        unsigned pk = pack_h2(h_old, hpart);
        ((unsigned*)states_h)[(bt << 9) + (u0 >> 1) + (l >> 1)] = pk;
        if (pk == 0xAAAAAAAAu) pk ^= 1u;
        __hip_atomic_store(&h16[(bt << 9) + (u0 >> 1) + (l >> 1)], pk,
                           __ATOMIC_RELAXED, __HIP_MEMORY_SCOPE_AGENT);
      }
      if (t + 1 < 1024) {
        size_t gb = (bt + 1) * 3072;
        g_r = gi[gb + u0 + l];
        g_z = gi[gb + 1024 + u0 + l];
        g_n = gi[gb + 2048 + u0 + l];
      }
    }
    // no third barrier: post-B2 hh2 rewrites touch nothing the gate phase reads
  }
}

// ------------------------------ slot scan ----------------------------------
// 1 WG (256 thr) per batch. slots[64][128] f32 in LDS, float4-XOR-swizzled:
// element (s,d) at  s*128 + (((d>>2) ^ (s&7))<<2) + (d&3)  -> all row- and
// column-order b128 traversals are bank-conflict-free.
__global__ __launch_bounds__(256) void k_slot(
    const float* __restrict__ act2,       // [4096][3072]: rq|wq|wv|wg|...
    const float* __restrict__ slot_init,  // [64][128]
    _Float16* __restrict__ rv_h)          // [4096][128]
{
  const int b = blockIdx.x;
  const int tid = threadIdx.x;
  __shared__ __attribute__((aligned(16))) float S[64 * 128];
  __shared__ __attribute__((aligned(16))) float lin[2][456];
  __shared__ float pr[4 * 65], pw[4 * 65];
  __shared__ float ar[64], aws[64];
  __shared__ __attribute__((aligned(16))) float rvp[8 * 128];

  for (int k = tid; k < 8192; k += 256) {
    int s = k >> 7, d = k & 127;
    S[(s << 7) + ((((d >> 2) ^ (s & 7))) << 2) + (d & 3)] = slot_init[k];
  }

  const size_t arow = (size_t)b << 10;
  float2 pf = {0.f, 0.f};
  if (tid < 224) {
    float2 v0 = *(const float2*)(act2 + arow * 3072 + (tid << 1));
    *(float2*)&lin[0][tid << 1] = v0;                       // lin(t=0)
    pf = *(const float2*)(act2 + (arow + 1) * 3072 + (tid << 1));  // lin(t=1)
  }
  const int q_ = tid >> 6, s_ = tid & 63;        // phase A mapping
  const int oct = tid >> 5, dc = tid & 31;       // phase C mapping
  __syncthreads();

  for (int t = 0; t < 1024; ++t) {
    const int buf = t & 1;
    // ---- A: dual dot partials (thread = (s, col-quarter q)) ----
    {
      const float4* Srow = (const float4*)&S[s_ << 7];
      const float4* rq4 = (const float4*)&lin[buf][q_ << 5];
      const float4* wq4 = (const float4*)&lin[buf][128 + (q_ << 5)];
      float pa = 0.f, pb = 0.f;
#pragma unroll
      for (int i = 0; i < 8; ++i) {
        float4 v = Srow[(q_ << 3) + (i ^ (s_ & 7))];
        float4 a = rq4[i];
        float4 c = wq4[i];
        pa += v.x * a.x + v.y * a.y + v.z * a.z + v.w * a.w;
        pb += v.x * c.x + v.y * c.y + v.z * c.z + v.w * c.w;
      }
      pr[q_ * 65 + s_] = pa;
      pw[q_ * 65 + s_] = pb;
    }
    __syncthreads();                              // B1

    // ---- B: softmaxes (waves 0,1) + previous-step rv fold (wave 2) ----
    if (tid < 64) {
      float lg = pr[tid] + pr[65 + tid] + pr[130 + tid] + pr[195 + tid];
      float mx = lg;
#pragma unroll
      for (int m = 1; m <= 32; m <<= 1) mx = fmaxf(mx, __shfl_xor(mx, m, 64));
      float e = __expf(lg - mx);
      float sm = e;
#pragma unroll
      for (int m = 1; m <= 32; m <<= 1) sm += __shfl_xor(sm, m, 64);
      ar[tid] = e / sm;
    } else if (tid < 128) {
      int s = tid - 64;
      float lg = pw[s] + pw[65 + s] + pw[130 + s] + pw[195 + s];
      float mx = lg;
#pragma unroll
      for (int m = 1; m <= 32; m <<= 1) mx = fmaxf(mx, __shfl_xor(mx, m, 64));
      float e = __expf(lg - mx);
      float sm = e;
#pragma unroll
      for (int m = 1; m <= 32; m <<= 1) sm += __shfl_xor(sm, m, 64);
      aws[s] = (e / sm) * lin[buf][384 + s];
    } else if (tid < 160 && t > 0) {
      int d4 = tid - 128;                         // 0..31
      float x = 0.f, y = 0.f, z = 0.f, w = 0.f;
#pragma unroll
      for (int o = 0; o < 8; ++o) {
        float4 v = *(const float4*)&rvp[(o << 7) + (d4 << 2)];
        x += v.x; y += v.y; z += v.z; w += v.w;
      }
      uint2 pk; pk.x = pack_h2(x, y); pk.y = pack_h2(z, w);
      *(uint2*)(rv_h + ((arow + (t - 1)) << 7) + (d4 << 2)) = pk;
    }
    __syncthreads();                              // B2

    // ---- C: fused read_vec + slot update (thread = (d-quad dc, s-oct)) ----
    if (tid < 224) {
      *(float2*)&lin[buf ^ 1][tid << 1] = pf;     // publish lin(t+1)
      if (t + 2 < 1024)
        pf = *(const float2*)(act2 + (arow + t + 2) * 3072 + (tid << 1));
    }
    {
      float4 wv4 = *(const float4*)&lin[buf][256 + (dc << 2)];
      float rx = 0.f, ry = 0.f, rz = 0.f, rw = 0.f;
      const int s0 = oct << 3;
#pragma unroll
      for (int i = 0; i < 8; ++i) {
        int s = s0 + i;
        float a = ar[s];
        float wsv = aws[s];
        float fr = 1.f - wsv;
        float4* p = (float4*)&S[s << 7] + (dc ^ (s & 7));
        float4 v = *p;
        rx += a * v.x; ry += a * v.y; rz += a * v.z; rw += a * v.w;
        v.x = v.x * fr + wv4.x * wsv;
        v.y = v.y * fr + wv4.y * wsv;
        v.z = v.z * fr + wv4.z * wsv;
        v.w = v.w * fr + wv4.w * wsv;
        *p = v;
      }
      float4 out; out.x = rx; out.y = ry; out.z = rz; out.w = rw;
      *(float4*)&rvp[(oct << 7) + (dc << 2)] = out;
    }
    __syncthreads();                              // B3
  }
  // final fold (t = 1023)
  if (tid < 32) {
    float x = 0.f, y = 0.f, z = 0.f, w = 0.f;
#pragma unroll
    for (int o = 0; o < 8; ++o) {
      float4 v = *(const float4*)&rvp[(o << 7) + (tid << 2)];
      x += v.x; y += v.y; z += v.z; w += v.w;
    }
    uint2 pk; pk.x = pack_h2(x, y); pk.y = pack_h2(z, w);
    *(uint2*)(rv_h + ((arow + 1023) << 7) + (tid << 2)) = pk;
  }
}

// ---------------------------- small utilities ------------------------------
__global__ void k_f32_to_f16_v8(const float* __restrict__ src,
                                _Float16* __restrict__ dst, int n8) {
  int i = blockIdx.x * 256 + threadIdx.x;
  if (i >= n8) return;
  float4 a = *(const float4*)(src + ((size_t)i << 3));
  float4 b = *(const float4*)(src + ((size_t)i << 3) + 4);
  f16x8 o;
  o[0] = (_Float16)a.x; o[1] = (_Float16)a.y; o[2] = (_Float16)a.z; o[3] = (_Float16)a.w;
  o[4] = (_Float16)b.x; o[5] = (_Float16)b.y; o[6] = (_Float16)b.z; o[7] = (_Float16)b.w;
  *(f16x8*)(dst + ((size_t)i << 3)) = o;
}

__global__ void k_build_wcat(const float* __restrict__ rq, const float* __restrict__ wq,
                             const float* __restrict__ wvw, const float* __restrict__ wg,
                             const float* __restrict__ hf, const float* __restrict__ rm,
                             _Float16* __restrict__ out) {
  int idx = blockIdx.x * 256 + threadIdx.x;
  if (idx >= 3072 * 1024) return;
  int row = idx >> 10, col = idx & 1023;
  float v;
  if      (row < 128)  v = rq[row * 1024 + col];
  else if (row < 256)  v = wq[(row - 128) * 1024 + col];
  else if (row < 384)  v = wvw[(row - 256) * 1024 + col];
  else if (row < 448)  v = wg[(row - 384) * 1024 + col];
  else if (row < 2496) v = hf[(row - 448) * 1024 + col];
  else if (row < 3008) v = rm[(row - 2496) * 1024 + col];
  else v = 0.f;
  out[idx] = (_Float16)v;
}

__global__ void k_build_biascat(const float* __restrict__ rq, const float* __restrict__ wq,
                                const float* __restrict__ wvb, const float* __restrict__ wg,
                                const float* __restrict__ hf, const float* __restrict__ rm,
                                float* __restrict__ out) {
  int r = blockIdx.x * 256 + threadIdx.x;
  if (r >= 3072) return;
  float v;
  if      (r < 128)  v = rq[r];
  else if (r < 256)  v = wq[r - 128];
  else if (r < 384)  v = wvb[r - 256];
  else if (r < 448)  v = wg[r - 384];
  else if (r < 2496) v = hf[r - 448];
  else if (r < 3008) v = rm[r - 2496];
  else v = 0.f;
  out[r] = v;
}

__global__ void k_gather_x(const int* __restrict__ ids,
                           const _Float16* __restrict__ emb_h,
                           _Float16* __restrict__ x_h) {
  int row = blockIdx.x;
  int id = ids[row];
  const unsigned* s = (const unsigned*)(emb_h + ((size_t)id << 9));
  unsigned* d = (unsigned*)(x_h + ((size_t)row << 9));
  d[threadIdx.x] = s[threadIdx.x];
}

__global__ void k_fill_u32(unsigned* __restrict__ p, unsigned v, int n) {
  int i = blockIdx.x * 256 + threadIdx.x;
  if (i < n) p[i] = v;
}

__global__ void k_mix(const float* __restrict__ base, const float* __restrict__ act2,
                      const float* __restrict__ retr, _Float16* __restrict__ out) {
  int idx = blockIdx.x * 256 + threadIdx.x;
  if (idx >= 4096 * 512) return;
  int r = idx >> 9, e = idx & 511;
  float v = base[idx] + act2[(size_t)r * 3072 + 2496 + e] * retr[idx];
  out[idx] = (_Float16)v;
}

// ------------------------------- launcher ----------------------------------
extern "C" void kernel_launch(void* const* d_in, const int* in_sizes, int n_in,
                              void* d_out, int out_size, void* d_ws, size_t ws_size,
                              hipStream_t stream)
{
  const int*   ids   = (const int*)d_in[0];
  const float* emb   = (const float*)d_in[1];
  const float* w_ih  = (const float*)d_in[2];
  const float* w_hh  = (const float*)d_in[3];
  const float* b_ih  = (const float*)d_in[4];
  const float* b_hh  = (const float*)d_in[5];
  const float* hf_w  = (const float*)d_in[6];
  const float* hf_b  = (const float*)d_in[7];
  const float* hp_w  = (const float*)d_in[8];
  const float* hp_b  = (const float*)d_in[9];
  const float* o_b   = (const float*)d_in[10];
  const float* sinit = (const float*)d_in[11];
  const float* rq_w  = (const float*)d_in[12];
  const float* rq_b  = (const float*)d_in[13];
  const float* wq_w  = (const float*)d_in[14];
  const float* wq_b  = (const float*)d_in[15];
  const float* wv_w  = (const float*)d_in[16];
  const float* wv_b  = (const float*)d_in[17];
  const float* wg_w  = (const float*)d_in[18];
  const float* wg_b  = (const float*)d_in[19];
  const float* rm_w  = (const float*)d_in[20];
  const float* rm_b  = (const float*)d_in[21];
  const float* s2f_w = (const float*)d_in[22];
  const float* s2f_b = (const float*)d_in[23];

  char* ws = (char*)d_ws;
  _Float16* emb_h   = (_Float16*)(ws + 0);          // 32,768,000
  _Float16* x_h     = (_Float16*)(ws + 32768000);   //  4,194,304
  _Float16* wih_h   = (_Float16*)(ws + 36962304);   //  3,145,728
  _Float16* wcat_h  = (_Float16*)(ws + 40108032);   //  6,291,456
  float*    biascat = (float*)   (ws + 46399488);   //     12,288
  _Float16* hpw_h   = (_Float16*)(ws + 46411776);   //  2,097,152
  _Float16* s2f_h   = (_Float16*)(ws + 48508928);   //    131,072
  float*    gi      = (float*)   (ws + 48640000);   // 50,331,648
  float*    act2    = (float*)   (ws + 98971648);   // 50,331,648
  unsigned* h16     = (unsigned*)(ws + 149303296);  //  8,388,608
  _Float16* states_h= (_Float16*)(ws + 166080512);  //  8,388,608
  _Float16* headh   = (_Float16*)(ws + 174469120);  // 16,777,216
  _Float16* rv_h    = (_Float16*)(ws + 191246336);  //  1,048,576
  float*    base    = (float*)   (ws + 192294912);  //  8,388,608
  float*    retr    = (float*)   (ws + 200683520);  //  8,388,608
  _Float16* mixed_h = (_Float16*)(ws + 209072128);  //  4,194,304

  float* out = (float*)d_out;

  k_f32_to_f16_v8<<<8000, 256, 0, stream>>>(emb, emb_h, 2048000);
  k_f32_to_f16_v8<<<768, 256, 0, stream>>>(w_ih, wih_h, 196608);
  k_f32_to_f16_v8<<<512, 256, 0, stream>>>(hp_w, hpw_h, 131072);
  k_f32_to_f16_v8<<<32, 256, 0, stream>>>(s2f_w, s2f_h, 8192);
  k_build_wcat<<<12288, 256, 0, stream>>>(rq_w, wq_w, wv_w, wg_w, hf_w, rm_w, wcat_h);
  k_build_biascat<<<12, 256, 0, stream>>>(rq_b, wq_b, wv_b, wg_b, hf_b, rm_b, biascat);
  k_gather_x<<<4096, 256, 0, stream>>>(ids, emb_h, x_h);
  k_fill_u32<<<8192, 256, 0, stream>>>(h16, 0xAAAAAAAAu, 2097152);

  k_gemm_bt<0><<<dim3(24, 32), 256, 0, stream>>>(x_h, wih_h, b_ih, gi, nullptr, 3072, 512);
  k_gru<<<256, 256, 0, stream>>>(gi, w_hh, b_hh, h16, states_h);
  k_gemm_bt<1><<<dim3(24, 32), 256, 0, stream>>>(states_h, wcat_h, biascat, act2, headh, 3072, 1024);
  k_slot<<<4, 256, 0, stream>>>(act2, sinit, rv_h);
  k_gemm_bt<0><<<dim3(4, 32), 256, 0, stream>>>(headh, hpw_h, hp_b, base, nullptr, 512, 2048);
  k_gemm_bt<0><<<dim3(4, 32), 256, 0, stream>>>(rv_h, s2f_h, s2f_b, retr, nullptr, 512, 128);
  k_mix<<<8192, 256, 0, stream>>>(base, act2, retr, mixed_h);
  k_gemm_bt<0><<<dim3(250, 32), 256, 0, stream>>>(mixed_h, emb_h, o_b, out, nullptr, 32000, 512);
}